// Round 1
// baseline (120.004 us; speedup 1.0000x reference)
//
#include <hip/hip_runtime.h>
#include <hip/hip_bf16.h>

typedef float f32x4 __attribute__((ext_vector_type(4)));
typedef __bf16 bf16x8 __attribute__((ext_vector_type(8)));
typedef __bf16 bf16x4 __attribute__((ext_vector_type(4)));

constexpr int C = 256;
constexpr int N = 2304;           // 48*48 tokens per batch
constexpr int T = 2 * N;          // total tokens

#if __has_builtin(__builtin_amdgcn_exp2f)
#define EXP2F(x) __builtin_amdgcn_exp2f(x)
#else
#define EXP2F(x) exp2f(x)
#endif

__device__ __forceinline__ bf16x8 load_bf8(const __bf16* p) {
    return *reinterpret_cast<const bf16x8*>(p);
}

// ---------------- kernel 0: convert Wq/Wk/Wv/Wo to bf16 ----------------
__global__ void wconv_kernel(const float* __restrict__ Wq, const float* __restrict__ Wk,
                             const float* __restrict__ Wv, const float* __restrict__ Wo,
                             __bf16* __restrict__ Wb) {
    int idx = blockIdx.x * 256 + threadIdx.x;   // 16384 threads, 4 f32 each per matrix
    const float* srcs[4] = {Wq, Wk, Wv, Wo};
    for (int m = 0; m < 4; ++m) {
        float4 v = reinterpret_cast<const float4*>(srcs[m])[idx];
        bf16x4 o = { (__bf16)v.x, (__bf16)v.y, (__bf16)v.z, (__bf16)v.w };
        reinterpret_cast<bf16x4*>(Wb + m * 65536)[idx] = o;
    }
}

// ---------------- kernel 1: gate + transpose to token-major bf16 ----------------
// xT[t][c] = bf16(x), gxT[t][c] = bf16(x * (1 - (Wg[c]*u[t] + bg[c])))
__global__ void prep_kernel(const float* __restrict__ x, const float* __restrict__ u,
                            const float* __restrict__ Wg, const float* __restrict__ bg,
                            __bf16* __restrict__ xT, __bf16* __restrict__ gxT) {
    __shared__ float tile[64][65];
    int b = blockIdx.z, c0 = blockIdx.y * 64, n0 = blockIdx.x * 64;
    int t = threadIdx.x;
    const float* xp = x + (b * C + c0) * N + n0;
    #pragma unroll
    for (int r = 0; r < 16; ++r) {
        int cl = r * 4 + (t >> 6);
        int nl = t & 63;
        tile[cl][nl] = xp[cl * N + nl];
    }
    __syncthreads();
    int cq = (t & 15) * 4;
    #pragma unroll
    for (int it = 0; it < 4; ++it) {
        int nl = it * 16 + (t >> 4);
        float uv = u[b * N + n0 + nl];
        bf16x4 xo, go;
        #pragma unroll
        for (int j = 0; j < 4; ++j) {
            int c = c0 + cq + j;
            float xv = tile[cq + j][nl];
            float gate = 1.0f - (Wg[c] * uv + bg[c]);
            xo[j] = (__bf16)xv;
            go[j] = (__bf16)(xv * gate);
        }
        int tok = b * N + n0 + nl;
        *reinterpret_cast<bf16x4*>(xT + (long)tok * C + c0 + cq) = xo;
        *reinterpret_cast<bf16x4*>(gxT + (long)tok * C + c0 + cq) = go;
    }
}

// ---------------- kernel 2: QKV projections (bf16 MFMA) ----------------
// Q[bh][n][d], K[bh][m][d] (pre-scaled by SCALE*log2e*(1-u[m])), V[bh][d][n]
__global__ __launch_bounds__(256) void qkv_kernel(const __bf16* __restrict__ Wb,
    const __bf16* __restrict__ xT, const __bf16* __restrict__ gxT,
    const float* __restrict__ bq, const float* __restrict__ bk, const float* __restrict__ bv,
    const float* __restrict__ u,
    __bf16* __restrict__ Q, __bf16* __restrict__ K, __bf16* __restrict__ V) {
    int proj = blockIdx.z;            // 0=q,1=k,2=v
    int o0 = blockIdx.y * 64;
    int t0 = blockIdx.x * 64;
    int wave = threadIdx.x >> 6, lane = threadIdx.x & 63;
    int g = lane >> 4, r = lane & 15;
    int ow = o0 + wave * 16;
    const __bf16* W = Wb + proj * 65536;
    const __bf16* inp = (proj == 2) ? xT : gxT;
    f32x4 acc[4] = {};
    for (int k = 0; k < 8; ++k) {
        bf16x8 a = load_bf8(W + (ow + r) * C + k * 32 + g * 8);
        #pragma unroll
        for (int tb = 0; tb < 4; ++tb) {
            bf16x8 bfr = load_bf8(inp + (long)(t0 + tb * 16 + r) * C + k * 32 + g * 8);
            acc[tb] = __builtin_amdgcn_mfma_f32_16x16x32_bf16(a, bfr, acc[tb], 0, 0, 0);
        }
    }
    const float* bias = (proj == 0) ? bq : (proj == 1) ? bk : bv;
    float bvw[4];
    #pragma unroll
    for (int i = 0; i < 4; ++i) bvw[i] = bias[ow + g * 4 + i];
    int h = ow >> 5, d0 = (ow & 31) + g * 4;
    const float SC = 0.17677669529663687f * 1.4426950408889634f;  // SCALE * log2(e)
    #pragma unroll
    for (int tb = 0; tb < 4; ++tb) {
        int t = t0 + tb * 16 + r;
        int b = t / N, n = t % N;
        if (proj == 2) {
            #pragma unroll
            for (int i = 0; i < 4; ++i)
                V[((long)(b * 8 + h) * 32 + d0 + i) * N + n] = (__bf16)(acc[tb][i] + bvw[i]);
        } else {
            float scale = (proj == 1) ? SC * (1.0f - u[t]) : 1.0f;
            bf16x4 outv;
            #pragma unroll
            for (int i = 0; i < 4; ++i) {
                float v = acc[tb][i] + bvw[i];
                v *= scale;
                if (proj == 0) v = acc[tb][i] + bvw[i];
                outv[i] = (__bf16)v;
            }
            __bf16* dst = (proj == 0) ? Q : K;
            *reinterpret_cast<bf16x4*>(dst + ((long)(b * 8 + h) * N + n) * 32 + d0) = outv;
        }
    }
}

// ---------------- kernel 3: flash attention (no-max softmax, swapped QK) ----------------
__global__ __launch_bounds__(256) void attn_kernel(const __bf16* __restrict__ Q,
    const __bf16* __restrict__ K, const __bf16* __restrict__ V,
    __bf16* __restrict__ aoT) {
    __shared__ __bf16 plds[4][1024];   // per-wave 16q x 64m P buffer
    int qblk = blockIdx.x, bh = blockIdx.y;
    int wave = threadIdx.x >> 6, lane = threadIdx.x & 63;
    int g = lane >> 4, r = lane & 15;
    int q0 = qblk * 64 + wave * 16;
    const __bf16* Qb = Q + (long)bh * N * 32;
    const __bf16* Kb = K + (long)bh * N * 32;
    const __bf16* Vb = V + (long)bh * 32 * N;
    bf16x8 qf = load_bf8(Qb + (q0 + r) * 32 + g * 8);   // B-frag: Q^T[d][q]
    f32x4 oacc[2] = {};
    float lrun = 0.0f;
    __bf16* pl = plds[wave];
    int swz = (r & 7) << 4;   // byte-offset XOR swizzle
    for (int m0 = 0; m0 < N; m0 += 64) {
        f32x4 s[4];
        #pragma unroll
        for (int t = 0; t < 4; ++t) {
            bf16x8 kf = load_bf8(Kb + (m0 + t * 16 + r) * 32 + g * 8);  // A-frag: K[m][d]
            f32x4 z = {};
            s[t] = __builtin_amdgcn_mfma_f32_16x16x32_bf16(kf, qf, z, 0, 0, 0);  // S^T tile
        }
        bf16x8 vf[2][2];
        #pragma unroll
        for (int ch = 0; ch < 2; ++ch)
            #pragma unroll
            for (int dt = 0; dt < 2; ++dt)
                vf[ch][dt] = load_bf8(Vb + (dt * 16 + r) * N + m0 + ch * 32 + g * 8);
        #pragma unroll
        for (int t = 0; t < 4; ++t) {
            bf16x4 pv;
            #pragma unroll
            for (int i = 0; i < 4; ++i) {
                float p = EXP2F(s[t][i]);   // scores pre-scaled by log2e: exact softmax
                lrun += p;
                pv[i] = (__bf16)p;
            }
            int off = r * 128 + ((t * 32 + g * 8) ^ swz);
            *reinterpret_cast<bf16x4*>(reinterpret_cast<char*>(pl) + off) = pv;
        }
        asm volatile("s_waitcnt lgkmcnt(0)" ::: "memory");
        #pragma unroll
        for (int ch = 0; ch < 2; ++ch) {
            int off = r * 128 + ((ch * 64 + g * 16) ^ swz);
            bf16x8 pf = *reinterpret_cast<const bf16x8*>(reinterpret_cast<char*>(pl) + off);
            oacc[0] = __builtin_amdgcn_mfma_f32_16x16x32_bf16(vf[ch][0], pf, oacc[0], 0, 0, 0);
            oacc[1] = __builtin_amdgcn_mfma_f32_16x16x32_bf16(vf[ch][1], pf, oacc[1], 0, 0, 0);
        }
        asm volatile("" ::: "memory");
    }
    float ltot = lrun;
    ltot += __shfl_xor(ltot, 16, 64);
    ltot += __shfl_xor(ltot, 32, 64);
    float inv = 1.0f / ltot;
    int b = bh >> 3, h = bh & 7;
    long tok = (long)b * N + q0 + r;
    #pragma unroll
    for (int dt = 0; dt < 2; ++dt) {
        bf16x4 ov;
        #pragma unroll
        for (int i = 0; i < 4; ++i) ov[i] = (__bf16)(oacc[dt][i] * inv);
        *reinterpret_cast<bf16x4*>(aoT + tok * C + h * 32 + dt * 16 + g * 4) = ov;
    }
}

// ---------------- kernel 4: output projection + bias + residual ----------------
__global__ __launch_bounds__(256) void outp_kernel(const __bf16* __restrict__ Wb,
    const __bf16* __restrict__ aoT, const float* __restrict__ bo,
    const float* __restrict__ x, float* __restrict__ out) {
    int o0 = blockIdx.y * 64;
    int t0 = blockIdx.x * 64;
    int wave = threadIdx.x >> 6, lane = threadIdx.x & 63;
    int g = lane >> 4, r = lane & 15;
    int ow = o0 + wave * 16;
    const __bf16* W = Wb + 3 * 65536;   // Wo
    f32x4 acc[4] = {};
    for (int k = 0; k < 8; ++k) {
        bf16x8 a = load_bf8(W + (ow + r) * C + k * 32 + g * 8);
        #pragma unroll
        for (int tb = 0; tb < 4; ++tb) {
            bf16x8 bfr = load_bf8(aoT + (long)(t0 + tb * 16 + r) * C + k * 32 + g * 8);
            acc[tb] = __builtin_amdgcn_mfma_f32_16x16x32_bf16(a, bfr, acc[tb], 0, 0, 0);
        }
    }
    float bvw[4];
    #pragma unroll
    for (int i = 0; i < 4; ++i) bvw[i] = bo[ow + g * 4 + i];
    #pragma unroll
    for (int tb = 0; tb < 4; ++tb) {
        int t = t0 + tb * 16 + r;
        int b = t / N, n = t % N;
        #pragma unroll
        for (int i = 0; i < 4; ++i) {
            long idx = ((long)b * C + ow + g * 4 + i) * N + n;
            out[idx] = acc[tb][i] + bvw[i] + x[idx];
        }
    }
}

extern "C" void kernel_launch(void* const* d_in, const int* in_sizes, int n_in,
                              void* d_out, int out_size, void* d_ws, size_t ws_size,
                              hipStream_t stream) {
    const float* x  = (const float*)d_in[0];
    const float* u  = (const float*)d_in[1];
    const float* Wq = (const float*)d_in[2];
    const float* bq = (const float*)d_in[3];
    const float* Wk = (const float*)d_in[4];
    const float* bk = (const float*)d_in[5];
    const float* Wv = (const float*)d_in[6];
    const float* bv = (const float*)d_in[7];
    const float* Wg = (const float*)d_in[8];
    const float* bg = (const float*)d_in[9];
    const float* Wo = (const float*)d_in[10];
    const float* bo = (const float*)d_in[11];
    float* out = (float*)d_out;

    char* ws = (char*)d_ws;
    size_t off = 0;
    auto alloc = [&](size_t bytes) {
        char* p = ws + off;
        off += (bytes + 255) & ~(size_t)255;
        return p;
    };
    __bf16* Wb  = (__bf16*)alloc((size_t)4 * 65536 * 2);
    __bf16* xT  = (__bf16*)alloc((size_t)T * C * 2);
    __bf16* gxT = (__bf16*)alloc((size_t)T * C * 2);
    __bf16* Qb  = (__bf16*)alloc((size_t)16 * N * 32 * 2);
    __bf16* Kb  = (__bf16*)alloc((size_t)16 * N * 32 * 2);
    __bf16* Vb  = (__bf16*)alloc((size_t)16 * N * 32 * 2);
    __bf16* aoT = (__bf16*)alloc((size_t)T * C * 2);

    wconv_kernel<<<64, 256, 0, stream>>>(Wq, Wk, Wv, Wo, Wb);
    prep_kernel<<<dim3(36, 4, 2), 256, 0, stream>>>(x, u, Wg, bg, xT, gxT);
    qkv_kernel<<<dim3(72, 4, 3), 256, 0, stream>>>(Wb, xT, gxT, bq, bk, bv, u, Qb, Kb, Vb);
    attn_kernel<<<dim3(36, 16), 256, 0, stream>>>(Qb, Kb, Vb, aoT);
    outp_kernel<<<dim3(72, 4), 256, 0, stream>>>(Wb, aoT, bo, x, out);
}

// Round 2
// 108.678 us; speedup vs baseline: 1.1042x; 1.1042x over previous
//
#include <hip/hip_runtime.h>
#include <hip/hip_bf16.h>

typedef float f32x4 __attribute__((ext_vector_type(4)));
typedef __bf16 bf16x8 __attribute__((ext_vector_type(8)));
typedef __bf16 bf16x4 __attribute__((ext_vector_type(4)));

constexpr int C = 256;
constexpr int N = 2304;           // 48*48 tokens per batch
constexpr int T = 2 * N;          // total tokens

#if __has_builtin(__builtin_amdgcn_exp2f)
#define EXP2F(x) __builtin_amdgcn_exp2f(x)
#else
#define EXP2F(x) exp2f(x)
#endif

__device__ __forceinline__ bf16x8 load_bf8(const __bf16* p) {
    return *reinterpret_cast<const bf16x8*>(p);
}

// ---------------- kernel 0: convert Wq/Wk/Wv/Wo to bf16 ----------------
__global__ void wconv_kernel(const float* __restrict__ Wq, const float* __restrict__ Wk,
                             const float* __restrict__ Wv, const float* __restrict__ Wo,
                             __bf16* __restrict__ Wb) {
    // 256 blocks: 64 blocks per matrix, one float4 per thread
    const float* srcs[4] = {Wq, Wk, Wv, Wo};
    int m = blockIdx.x >> 6;
    int idx = (blockIdx.x & 63) * 256 + threadIdx.x;   // [0, 16384)
    float4 v = reinterpret_cast<const float4*>(srcs[m])[idx];
    bf16x4 o = { (__bf16)v.x, (__bf16)v.y, (__bf16)v.z, (__bf16)v.w };
    reinterpret_cast<bf16x4*>(Wb + m * 65536)[idx] = o;
}

// ---------------- kernel 1: gate + transpose to token-major bf16 ----------------
// xT[t][c] = bf16(x), gxT[t][c] = bf16(x * (1 - (Wg[c]*u[t] + bg[c])))
__global__ void prep_kernel(const float* __restrict__ x, const float* __restrict__ u,
                            const float* __restrict__ Wg, const float* __restrict__ bg,
                            __bf16* __restrict__ xT, __bf16* __restrict__ gxT) {
    __shared__ float tile[64][65];
    int b = blockIdx.z, c0 = blockIdx.y * 64, n0 = blockIdx.x * 64;
    int t = threadIdx.x;
    const float* xp = x + (b * C + c0) * N + n0;
    #pragma unroll
    for (int r = 0; r < 16; ++r) {
        int cl = r * 4 + (t >> 6);
        int nl = t & 63;
        tile[cl][nl] = xp[cl * N + nl];
    }
    __syncthreads();
    int cq = (t & 15) * 4;
    #pragma unroll
    for (int it = 0; it < 4; ++it) {
        int nl = it * 16 + (t >> 4);
        float uv = u[b * N + n0 + nl];
        bf16x4 xo, go;
        #pragma unroll
        for (int j = 0; j < 4; ++j) {
            int c = c0 + cq + j;
            float xv = tile[cq + j][nl];
            float gate = 1.0f - (Wg[c] * uv + bg[c]);
            xo[j] = (__bf16)xv;
            go[j] = (__bf16)(xv * gate);
        }
        int tok = b * N + n0 + nl;
        *reinterpret_cast<bf16x4*>(xT + (long)tok * C + c0 + cq) = xo;
        *reinterpret_cast<bf16x4*>(gxT + (long)tok * C + c0 + cq) = go;
    }
}

// ---------------- kernel 2: QKV projections (bf16 MFMA) ----------------
// Q[bh][n][d], K[bh][m][d] (pre-scaled by SCALE*log2e*(1-u[m])), V[bh][d][n]
// 32-token tiles per block for TLP (latency-bound regime)
__global__ __launch_bounds__(256) void qkv_kernel(const __bf16* __restrict__ Wb,
    const __bf16* __restrict__ xT, const __bf16* __restrict__ gxT,
    const float* __restrict__ bq, const float* __restrict__ bk, const float* __restrict__ bv,
    const float* __restrict__ u,
    __bf16* __restrict__ Q, __bf16* __restrict__ K, __bf16* __restrict__ V) {
    int proj = blockIdx.z;            // 0=q,1=k,2=v
    int o0 = blockIdx.y * 64;
    int t0 = blockIdx.x * 32;
    int wave = threadIdx.x >> 6, lane = threadIdx.x & 63;
    int g = lane >> 4, r = lane & 15;
    int ow = o0 + wave * 16;
    const __bf16* W = Wb + proj * 65536;
    const __bf16* inp = (proj == 2) ? xT : gxT;
    f32x4 acc[2] = {};
    for (int k = 0; k < 8; ++k) {
        bf16x8 a = load_bf8(W + (ow + r) * C + k * 32 + g * 8);
        #pragma unroll
        for (int tb = 0; tb < 2; ++tb) {
            bf16x8 bfr = load_bf8(inp + (long)(t0 + tb * 16 + r) * C + k * 32 + g * 8);
            acc[tb] = __builtin_amdgcn_mfma_f32_16x16x32_bf16(a, bfr, acc[tb], 0, 0, 0);
        }
    }
    const float* bias = (proj == 0) ? bq : (proj == 1) ? bk : bv;
    float bvw[4];
    #pragma unroll
    for (int i = 0; i < 4; ++i) bvw[i] = bias[ow + g * 4 + i];
    int h = ow >> 5, d0 = (ow & 31) + g * 4;
    const float SC = 0.17677669529663687f * 1.4426950408889634f;  // SCALE * log2(e)
    #pragma unroll
    for (int tb = 0; tb < 2; ++tb) {
        int t = t0 + tb * 16 + r;
        int b = t / N, n = t % N;
        if (proj == 2) {
            #pragma unroll
            for (int i = 0; i < 4; ++i)
                V[((long)(b * 8 + h) * 32 + d0 + i) * N + n] = (__bf16)(acc[tb][i] + bvw[i]);
        } else {
            bf16x4 outv;
            if (proj == 1) {
                float scale = SC * (1.0f - u[t]);
                #pragma unroll
                for (int i = 0; i < 4; ++i) outv[i] = (__bf16)((acc[tb][i] + bvw[i]) * scale);
            } else {
                #pragma unroll
                for (int i = 0; i < 4; ++i) outv[i] = (__bf16)(acc[tb][i] + bvw[i]);
            }
            __bf16* dst = (proj == 0) ? Q : K;
            *reinterpret_cast<bf16x4*>(dst + ((long)(b * 8 + h) * N + n) * 32 + d0) = outv;
        }
    }
}

// ---------------- kernel 3: flash attention (no-max softmax, swapped QK) ----------------
// Key-split: 4 waves each handle 576 keys of the SAME 16-query tile; LDS combine.
__global__ __launch_bounds__(256) void attn_kernel(const __bf16* __restrict__ Q,
    const __bf16* __restrict__ K, const __bf16* __restrict__ V,
    __bf16* __restrict__ aoT) {
    __shared__ __bf16 plds[4][1024];   // per-wave 16q x 64m P buffer
    __shared__ float po[4][16][32];    // per-wave partial O
    __shared__ float lds_l[4][16];     // per-wave partial denominator
    int qt = blockIdx.x, bh = blockIdx.y;
    int wave = threadIdx.x >> 6, lane = threadIdx.x & 63;
    int g = lane >> 4, r = lane & 15;
    int q0 = qt * 16;
    const __bf16* Qb = Q + (long)bh * N * 32;
    const __bf16* Kb = K + (long)bh * N * 32;
    const __bf16* Vb = V + (long)bh * 32 * N;
    bf16x8 qf = load_bf8(Qb + (q0 + r) * 32 + g * 8);   // B-frag: Q^T[d][q]
    f32x4 oacc[2] = {};
    float lrun = 0.0f;
    __bf16* pl = plds[wave];
    int swz = (r & 7) << 4;   // byte-offset XOR swizzle
    int mbase = wave * 576;
    for (int it = 0; it < 9; ++it) {
        int m0 = mbase + it * 64;
        f32x4 s[4];
        #pragma unroll
        for (int t = 0; t < 4; ++t) {
            bf16x8 kf = load_bf8(Kb + (m0 + t * 16 + r) * 32 + g * 8);  // A-frag: K[m][d]
            f32x4 z = {};
            s[t] = __builtin_amdgcn_mfma_f32_16x16x32_bf16(kf, qf, z, 0, 0, 0);  // S^T tile
        }
        bf16x8 vf[2][2];
        #pragma unroll
        for (int ch = 0; ch < 2; ++ch)
            #pragma unroll
            for (int dt = 0; dt < 2; ++dt)
                vf[ch][dt] = load_bf8(Vb + (dt * 16 + r) * N + m0 + ch * 32 + g * 8);
        #pragma unroll
        for (int t = 0; t < 4; ++t) {
            bf16x4 pv;
            #pragma unroll
            for (int i = 0; i < 4; ++i) {
                float p = EXP2F(s[t][i]);   // scores pre-scaled by log2e: exact softmax
                lrun += p;
                pv[i] = (__bf16)p;
            }
            int off = r * 128 + ((t * 32 + g * 8) ^ swz);
            *reinterpret_cast<bf16x4*>(reinterpret_cast<char*>(pl) + off) = pv;
        }
        asm volatile("s_waitcnt lgkmcnt(0)" ::: "memory");
        #pragma unroll
        for (int ch = 0; ch < 2; ++ch) {
            int off = r * 128 + ((ch * 64 + g * 16) ^ swz);
            bf16x8 pf = *reinterpret_cast<const bf16x8*>(reinterpret_cast<char*>(pl) + off);
            oacc[0] = __builtin_amdgcn_mfma_f32_16x16x32_bf16(vf[ch][0], pf, oacc[0], 0, 0, 0);
            oacc[1] = __builtin_amdgcn_mfma_f32_16x16x32_bf16(vf[ch][1], pf, oacc[1], 0, 0, 0);
        }
        asm volatile("" ::: "memory");
    }
    // partial denominator for this wave's 576-key chunk (sum across g-groups)
    float ltot = lrun;
    ltot += __shfl_xor(ltot, 16, 64);
    ltot += __shfl_xor(ltot, 32, 64);
    // stash partials (each wave writes only its own slice -> no barrier needed before)
    #pragma unroll
    for (int dt = 0; dt < 2; ++dt)
        *reinterpret_cast<f32x4*>(&po[wave][r][dt * 16 + g * 4]) = oacc[dt];
    if (g == 0) lds_l[wave][r] = ltot;
    __syncthreads();
    // combine 4 key-chunks, normalize, write
    int b = bh >> 3, h = bh & 7;
    int tid = threadIdx.x;
    #pragma unroll
    for (int idx = tid; idx < 512; idx += 256) {
        int q = idx >> 5, d = idx & 31;
        float s = po[0][q][d] + po[1][q][d] + po[2][q][d] + po[3][q][d];
        float linv = 1.0f / (lds_l[0][q] + lds_l[1][q] + lds_l[2][q] + lds_l[3][q]);
        aoT[(long)(b * N + q0 + q) * C + h * 32 + d] = (__bf16)(s * linv);
    }
}

// ---------------- kernel 4: output projection + bias + residual ----------------
__global__ __launch_bounds__(256) void outp_kernel(const __bf16* __restrict__ Wb,
    const __bf16* __restrict__ aoT, const float* __restrict__ bo,
    const float* __restrict__ x, float* __restrict__ out) {
    int o0 = blockIdx.y * 64;
    int t0 = blockIdx.x * 32;
    int wave = threadIdx.x >> 6, lane = threadIdx.x & 63;
    int g = lane >> 4, r = lane & 15;
    int ow = o0 + wave * 16;
    const __bf16* W = Wb + 3 * 65536;   // Wo
    f32x4 acc[2] = {};
    for (int k = 0; k < 8; ++k) {
        bf16x8 a = load_bf8(W + (ow + r) * C + k * 32 + g * 8);
        #pragma unroll
        for (int tb = 0; tb < 2; ++tb) {
            bf16x8 bfr = load_bf8(aoT + (long)(t0 + tb * 16 + r) * C + k * 32 + g * 8);
            acc[tb] = __builtin_amdgcn_mfma_f32_16x16x32_bf16(a, bfr, acc[tb], 0, 0, 0);
        }
    }
    float bvw[4];
    #pragma unroll
    for (int i = 0; i < 4; ++i) bvw[i] = bo[ow + g * 4 + i];
    #pragma unroll
    for (int tb = 0; tb < 2; ++tb) {
        int t = t0 + tb * 16 + r;
        int b = t / N, n = t % N;
        #pragma unroll
        for (int i = 0; i < 4; ++i) {
            long idx = ((long)b * C + ow + g * 4 + i) * N + n;
            out[idx] = acc[tb][i] + bvw[i] + x[idx];
        }
    }
}

extern "C" void kernel_launch(void* const* d_in, const int* in_sizes, int n_in,
                              void* d_out, int out_size, void* d_ws, size_t ws_size,
                              hipStream_t stream) {
    const float* x  = (const float*)d_in[0];
    const float* u  = (const float*)d_in[1];
    const float* Wq = (const float*)d_in[2];
    const float* bq = (const float*)d_in[3];
    const float* Wk = (const float*)d_in[4];
    const float* bk = (const float*)d_in[5];
    const float* Wv = (const float*)d_in[6];
    const float* bv = (const float*)d_in[7];
    const float* Wg = (const float*)d_in[8];
    const float* bg = (const float*)d_in[9];
    const float* Wo = (const float*)d_in[10];
    const float* bo = (const float*)d_in[11];
    float* out = (float*)d_out;

    char* ws = (char*)d_ws;
    size_t off = 0;
    auto alloc = [&](size_t bytes) {
        char* p = ws + off;
        off += (bytes + 255) & ~(size_t)255;
        return p;
    };
    __bf16* Wb  = (__bf16*)alloc((size_t)4 * 65536 * 2);
    __bf16* xT  = (__bf16*)alloc((size_t)T * C * 2);
    __bf16* gxT = (__bf16*)alloc((size_t)T * C * 2);
    __bf16* Qb  = (__bf16*)alloc((size_t)16 * N * 32 * 2);
    __bf16* Kb  = (__bf16*)alloc((size_t)16 * N * 32 * 2);
    __bf16* Vb  = (__bf16*)alloc((size_t)16 * N * 32 * 2);
    __bf16* aoT = (__bf16*)alloc((size_t)T * C * 2);

    wconv_kernel<<<256, 256, 0, stream>>>(Wq, Wk, Wv, Wo, Wb);
    prep_kernel<<<dim3(36, 4, 2), 256, 0, stream>>>(x, u, Wg, bg, xT, gxT);
    qkv_kernel<<<dim3(144, 4, 3), 256, 0, stream>>>(Wb, xT, gxT, bq, bk, bv, u, Qb, Kb, Vb);
    attn_kernel<<<dim3(144, 16), 256, 0, stream>>>(Qb, Kb, Vb, aoT);
    outp_kernel<<<dim3(144, 4), 256, 0, stream>>>(Wb, aoT, bo, x, out);
}

// Round 3
// 80.958 us; speedup vs baseline: 1.4823x; 1.3424x over previous
//
#include <hip/hip_runtime.h>
#include <hip/hip_bf16.h>

typedef float f32x4 __attribute__((ext_vector_type(4)));
typedef __bf16 bf16x8 __attribute__((ext_vector_type(8)));
typedef __bf16 bf16x4 __attribute__((ext_vector_type(4)));

constexpr int C = 256;
constexpr int N = 2304;           // 48*48 tokens per batch
constexpr int T = 2 * N;          // total tokens

#if __has_builtin(__builtin_amdgcn_exp2f)
#define EXP2F(x) __builtin_amdgcn_exp2f(x)
#else
#define EXP2F(x) exp2f(x)
#endif

__device__ __forceinline__ bf16x8 load_bf8(const __bf16* p) {
    return *reinterpret_cast<const bf16x8*>(p);
}

// ---------------- kernel 0: convert Wq/Wk/Wv/Wo to bf16 ----------------
__global__ void wconv_kernel(const float* __restrict__ Wq, const float* __restrict__ Wk,
                             const float* __restrict__ Wv, const float* __restrict__ Wo,
                             __bf16* __restrict__ Wb) {
    const float* srcs[4] = {Wq, Wk, Wv, Wo};
    int m = blockIdx.x >> 6;
    int idx = (blockIdx.x & 63) * 256 + threadIdx.x;   // [0, 16384)
    float4 v = reinterpret_cast<const float4*>(srcs[m])[idx];
    bf16x4 o = { (__bf16)v.x, (__bf16)v.y, (__bf16)v.z, (__bf16)v.w };
    reinterpret_cast<bf16x4*>(Wb + m * 65536)[idx] = o;
}

// ---------------- kernel 1: gate + transpose to token-major bf16 ----------------
__global__ void prep_kernel(const float* __restrict__ x, const float* __restrict__ u,
                            const float* __restrict__ Wg, const float* __restrict__ bg,
                            __bf16* __restrict__ xT, __bf16* __restrict__ gxT) {
    __shared__ float tile[64][65];
    int b = blockIdx.z, c0 = blockIdx.y * 64, n0 = blockIdx.x * 64;
    int t = threadIdx.x;
    const float* xp = x + (b * C + c0) * N + n0;
    #pragma unroll
    for (int r = 0; r < 16; ++r) {
        int cl = r * 4 + (t >> 6);
        int nl = t & 63;
        tile[cl][nl] = xp[cl * N + nl];
    }
    __syncthreads();
    int cq = (t & 15) * 4;
    #pragma unroll
    for (int it = 0; it < 4; ++it) {
        int nl = it * 16 + (t >> 4);
        float uv = u[b * N + n0 + nl];
        bf16x4 xo, go;
        #pragma unroll
        for (int j = 0; j < 4; ++j) {
            int c = c0 + cq + j;
            float xv = tile[cq + j][nl];
            float gate = 1.0f - (Wg[c] * uv + bg[c]);
            xo[j] = (__bf16)xv;
            go[j] = (__bf16)(xv * gate);
        }
        int tok = b * N + n0 + nl;
        *reinterpret_cast<bf16x4*>(xT + (long)tok * C + c0 + cq) = xo;
        *reinterpret_cast<bf16x4*>(gxT + (long)tok * C + c0 + cq) = go;
    }
}

// ---------------- kernel 2: QKV projections (bf16 MFMA) ----------------
// Q[bh][n][d], K[bh][m][d] (pre-scaled by SCALE*log2e*(1-u[m])), V[bh][d][n]
__global__ __launch_bounds__(256) void qkv_kernel(const __bf16* __restrict__ Wb,
    const __bf16* __restrict__ xT, const __bf16* __restrict__ gxT,
    const float* __restrict__ bq, const float* __restrict__ bk, const float* __restrict__ bv,
    const float* __restrict__ u,
    __bf16* __restrict__ Q, __bf16* __restrict__ K, __bf16* __restrict__ V) {
    int proj = blockIdx.z;            // 0=q,1=k,2=v
    int o0 = blockIdx.y * 64;
    int t0 = blockIdx.x * 32;
    int wave = threadIdx.x >> 6, lane = threadIdx.x & 63;
    int g = lane >> 4, r = lane & 15;
    int ow = o0 + wave * 16;
    const __bf16* W = Wb + proj * 65536;
    const __bf16* inp = (proj == 2) ? xT : gxT;
    f32x4 acc[2] = {};
    for (int k = 0; k < 8; ++k) {
        bf16x8 a = load_bf8(W + (ow + r) * C + k * 32 + g * 8);
        #pragma unroll
        for (int tb = 0; tb < 2; ++tb) {
            bf16x8 bfr = load_bf8(inp + (long)(t0 + tb * 16 + r) * C + k * 32 + g * 8);
            acc[tb] = __builtin_amdgcn_mfma_f32_16x16x32_bf16(a, bfr, acc[tb], 0, 0, 0);
        }
    }
    const float* bias = (proj == 0) ? bq : (proj == 1) ? bk : bv;
    float bvw[4];
    #pragma unroll
    for (int i = 0; i < 4; ++i) bvw[i] = bias[ow + g * 4 + i];
    int h = ow >> 5, d0 = (ow & 31) + g * 4;
    const float SC = 0.17677669529663687f * 1.4426950408889634f;  // SCALE * log2(e)
    #pragma unroll
    for (int tb = 0; tb < 2; ++tb) {
        int t = t0 + tb * 16 + r;
        int b = t / N, n = t % N;
        if (proj == 2) {
            #pragma unroll
            for (int i = 0; i < 4; ++i)
                V[((long)(b * 8 + h) * 32 + d0 + i) * N + n] = (__bf16)(acc[tb][i] + bvw[i]);
        } else {
            bf16x4 outv;
            if (proj == 1) {
                float scale = SC * (1.0f - u[t]);
                #pragma unroll
                for (int i = 0; i < 4; ++i) outv[i] = (__bf16)((acc[tb][i] + bvw[i]) * scale);
            } else {
                #pragma unroll
                for (int i = 0; i < 4; ++i) outv[i] = (__bf16)(acc[tb][i] + bvw[i]);
            }
            __bf16* dst = (proj == 0) ? Q : K;
            *reinterpret_cast<bf16x4*>(dst + ((long)(b * 8 + h) * N + n) * 32 + d0) = outv;
        }
    }
}

// ---------------- kernel 3: flash attention ----------------
// 32 queries/block (2 q-tiles per wave), 4-way key-split, K prefetched 1 iter
// ahead, 1D grid XCD-pinned per head (lin id % 8 == bh % 8).
__global__ __launch_bounds__(256) void attn_kernel(const __bf16* __restrict__ Q,
    const __bf16* __restrict__ K, const __bf16* __restrict__ V,
    __bf16* __restrict__ aoT) {
    __shared__ __bf16 plds[4][2][1024];   // per-wave, per-qtile 16q x 64m P buffer
    __shared__ float po[4][2][16][32];    // per-wave partial O
    __shared__ float lds_l[4][2][16];     // per-wave partial denominator
    int id = blockIdx.x;
    int rest = id >> 3;
    int qc = rest % 72;
    int bh = (id & 7) + 8 * (rest / 72);
    int wave = threadIdx.x >> 6, lane = threadIdx.x & 63;
    int g = lane >> 4, r = lane & 15;
    int q0 = qc * 32;
    const __bf16* Qb = Q + (long)bh * N * 32;
    const __bf16* Kb = K + (long)bh * N * 32;
    const __bf16* Vb = V + (long)bh * 32 * N;
    bf16x8 qf0 = load_bf8(Qb + (q0 + r) * 32 + g * 8);        // B-frag q-tile 0
    bf16x8 qf1 = load_bf8(Qb + (q0 + 16 + r) * 32 + g * 8);   // B-frag q-tile 1
    int mbase = wave * 576;
    // K prefetch registers (explicit cur/next names; no runtime-indexed arrays)
    bf16x8 kc0 = load_bf8(Kb + (mbase +  0 + r) * 32 + g * 8);
    bf16x8 kc1 = load_bf8(Kb + (mbase + 16 + r) * 32 + g * 8);
    bf16x8 kc2 = load_bf8(Kb + (mbase + 32 + r) * 32 + g * 8);
    bf16x8 kc3 = load_bf8(Kb + (mbase + 48 + r) * 32 + g * 8);
    f32x4 oa00 = {}, oa01 = {}, oa10 = {}, oa11 = {};   // oa[qt][dt]
    float lr0 = 0.0f, lr1 = 0.0f;
    __bf16* pl0 = plds[wave][0];
    __bf16* pl1 = plds[wave][1];
    int swz = (r & 7) << 4;   // byte-offset XOR swizzle
    for (int it = 0; it < 9; ++it) {
        int m0 = mbase + it * 64;
        int mp = (it == 8) ? m0 : m0 + 64;   // clamp last prefetch (stays in-buffer)
        // V loads for current iter (consumed after exp+LDS, ~250cy of cover)
        bf16x8 vf00 = load_bf8(Vb + (     r) * N + m0      + g * 8);  // ch0 dt0
        bf16x8 vf01 = load_bf8(Vb + (16 + r) * N + m0      + g * 8);  // ch0 dt1
        bf16x8 vf10 = load_bf8(Vb + (     r) * N + m0 + 32 + g * 8);  // ch1 dt0
        bf16x8 vf11 = load_bf8(Vb + (16 + r) * N + m0 + 32 + g * 8);  // ch1 dt1
        // K prefetch for next iter (consumed next iter start, full-iter cover)
        bf16x8 kn0 = load_bf8(Kb + (mp +  0 + r) * 32 + g * 8);
        bf16x8 kn1 = load_bf8(Kb + (mp + 16 + r) * 32 + g * 8);
        bf16x8 kn2 = load_bf8(Kb + (mp + 32 + r) * 32 + g * 8);
        bf16x8 kn3 = load_bf8(Kb + (mp + 48 + r) * 32 + g * 8);
        f32x4 z = {};
        // ---- q-tile 0: QK^T, exp2, P-store ----
        {
            f32x4 s0 = __builtin_amdgcn_mfma_f32_16x16x32_bf16(kc0, qf0, z, 0, 0, 0);
            f32x4 s1 = __builtin_amdgcn_mfma_f32_16x16x32_bf16(kc1, qf0, z, 0, 0, 0);
            f32x4 s2 = __builtin_amdgcn_mfma_f32_16x16x32_bf16(kc2, qf0, z, 0, 0, 0);
            f32x4 s3 = __builtin_amdgcn_mfma_f32_16x16x32_bf16(kc3, qf0, z, 0, 0, 0);
            f32x4 sv[4] = {s0, s1, s2, s3};
            #pragma unroll
            for (int t = 0; t < 4; ++t) {
                bf16x4 pv;
                #pragma unroll
                for (int i = 0; i < 4; ++i) {
                    float p = EXP2F(sv[t][i]);
                    lr0 += p;
                    pv[i] = (__bf16)p;
                }
                int off = r * 128 + ((t * 32 + g * 8) ^ swz);
                *reinterpret_cast<bf16x4*>(reinterpret_cast<char*>(pl0) + off) = pv;
            }
        }
        // ---- q-tile 1 ----
        {
            f32x4 s0 = __builtin_amdgcn_mfma_f32_16x16x32_bf16(kc0, qf1, z, 0, 0, 0);
            f32x4 s1 = __builtin_amdgcn_mfma_f32_16x16x32_bf16(kc1, qf1, z, 0, 0, 0);
            f32x4 s2 = __builtin_amdgcn_mfma_f32_16x16x32_bf16(kc2, qf1, z, 0, 0, 0);
            f32x4 s3 = __builtin_amdgcn_mfma_f32_16x16x32_bf16(kc3, qf1, z, 0, 0, 0);
            f32x4 sv[4] = {s0, s1, s2, s3};
            #pragma unroll
            for (int t = 0; t < 4; ++t) {
                bf16x4 pv;
                #pragma unroll
                for (int i = 0; i < 4; ++i) {
                    float p = EXP2F(sv[t][i]);
                    lr1 += p;
                    pv[i] = (__bf16)p;
                }
                int off = r * 128 + ((t * 32 + g * 8) ^ swz);
                *reinterpret_cast<bf16x4*>(reinterpret_cast<char*>(pl1) + off) = pv;
            }
        }
        asm volatile("s_waitcnt lgkmcnt(0)" ::: "memory");
        // ---- PV: V-frags shared across both q-tiles ----
        #pragma unroll
        for (int ch = 0; ch < 2; ++ch) {
            int off = r * 128 + ((ch * 64 + g * 16) ^ swz);
            bf16x8 pf0 = *reinterpret_cast<const bf16x8*>(reinterpret_cast<char*>(pl0) + off);
            bf16x8 pf1 = *reinterpret_cast<const bf16x8*>(reinterpret_cast<char*>(pl1) + off);
            bf16x8 v0 = ch ? vf10 : vf00;
            bf16x8 v1 = ch ? vf11 : vf01;
            oa00 = __builtin_amdgcn_mfma_f32_16x16x32_bf16(v0, pf0, oa00, 0, 0, 0);
            oa01 = __builtin_amdgcn_mfma_f32_16x16x32_bf16(v1, pf0, oa01, 0, 0, 0);
            oa10 = __builtin_amdgcn_mfma_f32_16x16x32_bf16(v0, pf1, oa10, 0, 0, 0);
            oa11 = __builtin_amdgcn_mfma_f32_16x16x32_bf16(v1, pf1, oa11, 0, 0, 0);
        }
        asm volatile("" ::: "memory");
        kc0 = kn0; kc1 = kn1; kc2 = kn2; kc3 = kn3;
    }
    // per-wave partial denominators (per query row r within each tile)
    float lt0 = lr0;
    lt0 += __shfl_xor(lt0, 16, 64);
    lt0 += __shfl_xor(lt0, 32, 64);
    float lt1 = lr1;
    lt1 += __shfl_xor(lt1, 16, 64);
    lt1 += __shfl_xor(lt1, 32, 64);
    *reinterpret_cast<f32x4*>(&po[wave][0][r][g * 4])      = oa00;
    *reinterpret_cast<f32x4*>(&po[wave][0][r][16 + g * 4]) = oa01;
    *reinterpret_cast<f32x4*>(&po[wave][1][r][g * 4])      = oa10;
    *reinterpret_cast<f32x4*>(&po[wave][1][r][16 + g * 4]) = oa11;
    if (g == 0) {
        lds_l[wave][0][r] = lt0;
        lds_l[wave][1][r] = lt1;
    }
    __syncthreads();
    // combine 4 key-chunks, normalize, write (1024 outputs, 4 per thread)
    int tid = threadIdx.x;
    int d4 = (tid & 7) * 4;
    int qi = tid >> 3;          // 0..31
    int qt = qi >> 4, qq = qi & 15;
    f32x4 sum = *reinterpret_cast<f32x4*>(&po[0][qt][qq][d4]);
    float l = lds_l[0][qt][qq];
    #pragma unroll
    for (int w = 1; w < 4; ++w) {
        sum += *reinterpret_cast<f32x4*>(&po[w][qt][qq][d4]);
        l += lds_l[w][qt][qq];
    }
    float inv = 1.0f / l;
    bf16x4 ov;
    #pragma unroll
    for (int i = 0; i < 4; ++i) ov[i] = (__bf16)(sum[i] * inv);
    int b = bh >> 3, h = bh & 7;
    *reinterpret_cast<bf16x4*>(aoT + (long)(b * N + q0 + qt * 16 + qq) * C + h * 32 + d4) = ov;
}

// ---------------- kernel 4: output projection + bias + residual ----------------
__global__ __launch_bounds__(256) void outp_kernel(const __bf16* __restrict__ Wb,
    const __bf16* __restrict__ aoT, const float* __restrict__ bo,
    const float* __restrict__ x, float* __restrict__ out) {
    int o0 = blockIdx.y * 64;
    int t0 = blockIdx.x * 32;
    int wave = threadIdx.x >> 6, lane = threadIdx.x & 63;
    int g = lane >> 4, r = lane & 15;
    int ow = o0 + wave * 16;
    const __bf16* W = Wb + 3 * 65536;   // Wo
    f32x4 acc[2] = {};
    for (int k = 0; k < 8; ++k) {
        bf16x8 a = load_bf8(W + (ow + r) * C + k * 32 + g * 8);
        #pragma unroll
        for (int tb = 0; tb < 2; ++tb) {
            bf16x8 bfr = load_bf8(aoT + (long)(t0 + tb * 16 + r) * C + k * 32 + g * 8);
            acc[tb] = __builtin_amdgcn_mfma_f32_16x16x32_bf16(a, bfr, acc[tb], 0, 0, 0);
        }
    }
    float bvw[4];
    #pragma unroll
    for (int i = 0; i < 4; ++i) bvw[i] = bo[ow + g * 4 + i];
    #pragma unroll
    for (int tb = 0; tb < 2; ++tb) {
        int t = t0 + tb * 16 + r;
        int b = t / N, n = t % N;
        #pragma unroll
        for (int i = 0; i < 4; ++i) {
            long idx = ((long)b * C + ow + g * 4 + i) * N + n;
            out[idx] = acc[tb][i] + bvw[i] + x[idx];
        }
    }
}

extern "C" void kernel_launch(void* const* d_in, const int* in_sizes, int n_in,
                              void* d_out, int out_size, void* d_ws, size_t ws_size,
                              hipStream_t stream) {
    const float* x  = (const float*)d_in[0];
    const float* u  = (const float*)d_in[1];
    const float* Wq = (const float*)d_in[2];
    const float* bq = (const float*)d_in[3];
    const float* Wk = (const float*)d_in[4];
    const float* bk = (const float*)d_in[5];
    const float* Wv = (const float*)d_in[6];
    const float* bv = (const float*)d_in[7];
    const float* Wg = (const float*)d_in[8];
    const float* bg = (const float*)d_in[9];
    const float* Wo = (const float*)d_in[10];
    const float* bo = (const float*)d_in[11];
    float* out = (float*)d_out;

    char* ws = (char*)d_ws;
    size_t off = 0;
    auto alloc = [&](size_t bytes) {
        char* p = ws + off;
        off += (bytes + 255) & ~(size_t)255;
        return p;
    };
    __bf16* Wb  = (__bf16*)alloc((size_t)4 * 65536 * 2);
    __bf16* xT  = (__bf16*)alloc((size_t)T * C * 2);
    __bf16* gxT = (__bf16*)alloc((size_t)T * C * 2);
    __bf16* Qb  = (__bf16*)alloc((size_t)16 * N * 32 * 2);
    __bf16* Kb  = (__bf16*)alloc((size_t)16 * N * 32 * 2);
    __bf16* Vb  = (__bf16*)alloc((size_t)16 * N * 32 * 2);
    __bf16* aoT = (__bf16*)alloc((size_t)T * C * 2);

    wconv_kernel<<<256, 256, 0, stream>>>(Wq, Wk, Wv, Wo, Wb);
    prep_kernel<<<dim3(36, 4, 2), 256, 0, stream>>>(x, u, Wg, bg, xT, gxT);
    qkv_kernel<<<dim3(144, 4, 3), 256, 0, stream>>>(Wb, xT, gxT, bq, bk, bv, u, Qb, Kb, Vb);
    attn_kernel<<<1152, 256, 0, stream>>>(Qb, Kb, Vb, aoT);
    outp_kernel<<<dim3(144, 4), 256, 0, stream>>>(Wb, aoT, bo, x, out);
}